// Round 7
// baseline (706.295 us; speedup 1.0000x reference)
//
#include <hip/hip_runtime.h>
#include <hip/hip_bf16.h>
#include <cmath>

#define NNODES 100000
#define NGRAPHS 64
#define SHIFT 10
#define NPB 1024                 // nodes per bucket
#define NB 98                    // ceil(NNODES / NPB)
#define CAP 24576                // max edges per bucket region (exp 16384 +- 128)
#define BIN_CHUNK 4096
#define HSTRIDE 136              // LDS row stride in shorts (272B, 16B-aligned rows)

// Node-feature layout is XCD-SLICED: h[slice][node][16] bf16, slice = col/16.
// One slice = N*16*2B = 3.2MB < 4MB per-XCD L2. gather pins slice s to XCD s
// via blockIdx.x % NSL (default dispatch round-robins XCDs; NSL divides 8).

typedef __attribute__((ext_vector_type(8))) short bf16x8;
typedef __attribute__((ext_vector_type(4))) float f32x4;
typedef __attribute__((ext_vector_type(4))) unsigned int u32x4;

__device__ __forceinline__ float bf2f(unsigned short u) {
    unsigned int v = ((unsigned int)u) << 16;
    return __uint_as_float(v);
}
__device__ __forceinline__ unsigned short f2bf(float f) {
    unsigned int v = __float_as_uint(f);
    unsigned int r = (v + 0x7fffu + ((v >> 16) & 1u)) >> 16;
    return (unsigned short)r;
}

__device__ __forceinline__ void atomicMaxF(float* addr, float v) {
    if (v >= 0.f) atomicMax((int*)addr, __float_as_int(v));
    else          atomicMin((unsigned int*)addr, __float_as_uint(v));
}

// ---------------- x (f32 [N][64]) -> bf16 sliced [4][N][16] ----------------
__global__ void convert_kernel(u32x4* __restrict__ dst, const float* __restrict__ src, int N) {
    int tid = blockIdx.x * blockDim.x + threadIdx.x;
    if (tid >= N * 8) return;
    int n = tid >> 3, g = tid & 7;          // g: col group of 8
    float4 a = *(const float4*)(src + (size_t)n * 64 + g * 8);
    float4 b = *(const float4*)(src + (size_t)n * 64 + g * 8 + 4);
    unsigned short o[8] = { f2bf(a.x), f2bf(a.y), f2bf(a.z), f2bf(a.w),
                            f2bf(b.x), f2bf(b.y), f2bf(b.z), f2bf(b.w) };
    int s = g >> 1, q = g & 1;
    dst[((size_t)s * N + n) * 2 + q] = *(u32x4*)o;
}

// ---------------- CSR build (binned, no global histogram) ----------------
__global__ void init_gcur(int* __restrict__ gcur) {
    int b = threadIdx.x;
    if (b < NB) gcur[b] = b * CAP;
}

__global__ __launch_bounds__(256) void bin_kernel(unsigned int* __restrict__ binned,
                                                  int* __restrict__ gcur,
                                                  const int* __restrict__ ei, int E) {
    __shared__ int cnt[NB];
    __shared__ int gbase[NB];
    __shared__ int loff[NB];
    int t = threadIdx.x;
    int base = blockIdx.x * BIN_CHUNK;
    for (int i = t; i < NB; i += 256) { cnt[i] = 0; loff[i] = 0; }
    __syncthreads();
    unsigned int pk[16]; short bk[16]; int ne = 0;
#pragma unroll
    for (int i = 0; i < 16; ++i) {
        int e = base + t + i * 256;
        if (e < E) {
            int s = ei[e], d = ei[E + e];
            int b = d >> SHIFT;
            pk[ne] = ((unsigned int)s << SHIFT) | (unsigned int)(d & (NPB - 1));
            bk[ne] = (short)b;
            ne++;
            atomicAdd(&cnt[b], 1);
        }
    }
    __syncthreads();
    for (int i = t; i < NB; i += 256)
        gbase[i] = cnt[i] ? atomicAdd(&gcur[i], cnt[i]) : 0;
    __syncthreads();
    for (int i = 0; i < ne; ++i) {
        int b = bk[i];
        int pos = atomicAdd(&loff[b], 1);
        binned[gbase[b] + pos] = pk[i];
    }
}

__global__ void bucket_scan(int* __restrict__ bbase, const int* __restrict__ gcur) {
    if (threadIdx.x == 0 && blockIdx.x == 0) {
        int acc = 0;
        for (int b = 0; b < NB; ++b) { bbase[b] = acc; acc += gcur[b] - b * CAP; }
        bbase[NB] = acc;
    }
}

__global__ __launch_bounds__(256) void fill2_kernel(int* __restrict__ csr,
                                                    int* __restrict__ start,
                                                    const unsigned int* __restrict__ binned,
                                                    const int* __restrict__ gcur,
                                                    const int* __restrict__ bbase, int N) {
    __shared__ int cur[NPB];
    __shared__ int tsum[256];
    int b = blockIdx.x, t = threadIdx.x;
    int n0 = b << SHIFT;
    int nn = N - n0; if (nn > NPB) nn = NPB;
    int c = gcur[b] - b * CAP;
    int gb = bbase[b];
    const unsigned int* eb = binned + (size_t)b * CAP;
    for (int i = t; i < NPB; i += 256) cur[i] = 0;
    __syncthreads();
    for (int p = t; p < c; p += 256) atomicAdd(&cur[eb[p] & (NPB - 1)], 1);
    __syncthreads();
    int v[4]; int s = 0;
#pragma unroll
    for (int i = 0; i < 4; ++i) { v[i] = cur[t * 4 + i]; s += v[i]; }
    int x = s;
    tsum[t] = x;
    __syncthreads();
    for (int off = 1; off < 256; off <<= 1) {
        int y = (t >= off) ? tsum[t - off] : 0;
        __syncthreads();
        x += y;
        tsum[t] = x;
        __syncthreads();
    }
    int run = x - s + gb;
#pragma unroll
    for (int i = 0; i < 4; ++i) {
        int idx = t * 4 + i;
        cur[idx] = run;
        if (idx < nn) start[n0 + idx] = run;
        run += v[i];
    }
    __syncthreads();
    for (int p = t; p < c; p += 256) {
        unsigned int e = eb[p];
        int slot = atomicAdd(&cur[e & (NPB - 1)], 1);
        csr[slot] = (int)(e >> SHIFT);
    }
    if (t == 0 && b == 0) start[N] = bbase[NB];
}

// ---------------- sliced aggregation: out[i] = h[i] + sum_j h[j] ----------------
// grid = NSL * ceil(N/128); slice = blockIdx.x % NSL (XCD-pinned); 2 lanes/node.
template<int NSL>
__global__ __launch_bounds__(256) void gather_sliced(u32x4* __restrict__ outb,
                                                     const u32x4* __restrict__ h,
                                                     const int* __restrict__ start,
                                                     const int* __restrict__ csr, int N) {
    const int slice = blockIdx.x % NSL;
    int node = (blockIdx.x / NSL) * 128 + (threadIdx.x >> 1);
    if (node >= N) return;
    const int q = threadIdx.x & 1;
    const u32x4* hs = h + (size_t)slice * N * 2;
    size_t sidx = (size_t)2 * node + q;
    float acc[8];
    {
        u32x4 v = hs[sidx];
        const unsigned short* qd = (const unsigned short*)&v;
#pragma unroll
        for (int i = 0; i < 8; ++i) acc[i] = bf2f(qd[i]);
    }
    int p0 = __builtin_nontemporal_load(start + node);
    int p1 = __builtin_nontemporal_load(start + node + 1);
    if (p0 < p1) {
        int j = __builtin_nontemporal_load(csr + p0);
        for (int p = p0 + 1; p < p1; ++p) {
            int jn = __builtin_nontemporal_load(csr + p);
            u32x4 w = hs[(size_t)2 * j + q];
            const unsigned short* qw = (const unsigned short*)&w;
#pragma unroll
            for (int i = 0; i < 8; ++i) acc[i] += bf2f(qw[i]);
            j = jn;
        }
        u32x4 w = hs[(size_t)2 * j + q];
        const unsigned short* qw = (const unsigned short*)&w;
#pragma unroll
        for (int i = 0; i < 8; ++i) acc[i] += bf2f(qw[i]);
    }
    unsigned short o[8];
#pragma unroll
    for (int i = 0; i < 8; ++i) o[i] = f2bf(acc[i]);
    __builtin_nontemporal_store(*(u32x4*)o, outb + (size_t)slice * N * 2 + sidx);
}

// ---------------- W (K x 128 f32) -> MFMA B-fragment pack (bf16) ----------------
__global__ void pack_w_kernel(unsigned short* __restrict__ wp, const float* __restrict__ W, int K) {
    int t = blockIdx.x * blockDim.x + threadIdx.x;
    int total = (K / 32) * 8 * 64;
    if (t >= total) return;
    int l = t & 63;
    int n0 = (t >> 6) & 7;
    int kp = t >> 9;
    unsigned short o[8];
#pragma unroll
    for (int j = 0; j < 8; ++j)
        o[j] = f2bf(W[(size_t)(kp * 32 + (l >> 4) * 8 + j) * 128 + n0 * 16 + (l & 15)]);
    *(u32x4*)(wp + (size_t)t * 8) = *(u32x4*)o;
}

// ---------------- fused MLP: out = (relu(A@W1+b1))@W2 + b2 (A, out sliced) ----------------
template<int K1>
__global__ __launch_bounds__(256) void mfma_gemm_pair(const unsigned short* __restrict__ A,
                                                      const unsigned short* __restrict__ Wp1,
                                                      const float* __restrict__ bias1,
                                                      const unsigned short* __restrict__ Wp2,
                                                      const float* __restrict__ bias2,
                                                      unsigned short* __restrict__ out, int M) {
    __shared__ unsigned short hl[4][16 * HSTRIDE];
    const int l = threadIdx.x & 63;
    const int w = threadIdx.x >> 6;
    const int mbase = (blockIdx.x * 4 + w) * 16;
    const int kgrp = l >> 4;
    const int col = l & 15;
    int row_a = mbase + col;
    if (row_a >= M) row_a = M - 1;

    f32x4 acc[8];
#pragma unroll
    for (int i = 0; i < 8; ++i) acc[i] = (f32x4){0.f, 0.f, 0.f, 0.f};
#pragma unroll
    for (int kp = 0; kp < K1 / 32; ++kp) {
        // sliced A: col c0 = kp*32+kgrp*8 -> slice c0>>4, offset (kgrp&1)*8
        bf16x8 a = *(const bf16x8*)(A + ((size_t)((kp * 32 + kgrp * 8) >> 4) * M + row_a) * 16 + (kgrp & 1) * 8);
#pragma unroll
        for (int n0 = 0; n0 < 8; ++n0) {
            bf16x8 bfr = *(const bf16x8*)(Wp1 + ((size_t)(kp * 8 + n0) * 64 + l) * 8);
            acc[n0] = __builtin_amdgcn_mfma_f32_16x16x32_bf16(a, bfr, acc[n0], 0, 0, 0);
        }
    }

    unsigned short* hb = hl[w];
#pragma unroll
    for (int n0 = 0; n0 < 8; ++n0) {
        float bv = bias1[n0 * 16 + col];
#pragma unroll
        for (int r = 0; r < 4; ++r) {
            float v = acc[n0][r] + bv;
            v = fmaxf(v, 0.f);
            hb[(kgrp * 4 + r) * HSTRIDE + n0 * 16 + col] = f2bf(v);
        }
    }
    __syncthreads();

    f32x4 acc2[8];
#pragma unroll
    for (int i = 0; i < 8; ++i) acc2[i] = (f32x4){0.f, 0.f, 0.f, 0.f};
#pragma unroll
    for (int kp = 0; kp < 4; ++kp) {
        bf16x8 a2 = *(const bf16x8*)(hb + col * HSTRIDE + kp * 32 + kgrp * 8);
#pragma unroll
        for (int n0 = 0; n0 < 8; ++n0) {
            bf16x8 bfr = *(const bf16x8*)(Wp2 + ((size_t)(kp * 8 + n0) * 64 + l) * 8);
            acc2[n0] = __builtin_amdgcn_mfma_f32_16x16x32_bf16(a2, bfr, acc2[n0], 0, 0, 0);
        }
    }

#pragma unroll
    for (int n0 = 0; n0 < 8; ++n0) {
        float bv = bias2[n0 * 16 + col];
#pragma unroll
        for (int r = 0; r < 4; ++r) {
            int row = mbase + kgrp * 4 + r;
            if (row < M)
                out[((size_t)n0 * M + row) * 16 + col] = f2bf(acc2[n0][r] + bv);
        }
    }
}

// ---------------- pool + head ----------------
__global__ void init_pool_kernel(float* p) {
    int i = blockIdx.x * blockDim.x + threadIdx.x;
    if (i < NGRAPHS * 128) p[i] = -INFINITY;
}

__global__ __launch_bounds__(128) void pool_kernel(float* __restrict__ pooled,
                                                   const unsigned short* __restrict__ h,
                                                   const int* __restrict__ batch, int N) {
    const int f = threadIdx.x;
    const unsigned short* hs = h + (size_t)(f >> 4) * N * 16 + (f & 15);
    int n0 = blockIdx.x * 128;
    int n1 = n0 + 128;
    if (n1 > N) n1 = N;
    int cur = -1;
    float run = -INFINITY;
    for (int n = n0; n < n1; ++n) {
        int g = batch[n];
        if (g != cur) {
            if (cur >= 0) atomicMaxF(&pooled[cur * 128 + f], run);
            cur = g;
            run = -INFINITY;
        }
        run = fmaxf(run, bf2f(hs[(size_t)n * 16]));
    }
    if (cur >= 0) atomicMaxF(&pooled[cur * 128 + f], run);
}

__global__ __launch_bounds__(64) void head_kernel(float* __restrict__ out,
                                                  const float* __restrict__ pooled,
                                                  const float* __restrict__ w1,
                                                  const float* __restrict__ b1,
                                                  const float* __restrict__ w2,
                                                  const float* __restrict__ b2) {
    int g = blockIdx.x, t = threadIdx.x;
    __shared__ float a[64];
    __shared__ float o[10];
    __shared__ float red[2];
    const float* pg = pooled + g * 128;
    float acc = b1[t];
    for (int k = 0; k < 128; ++k) acc = fmaf(pg[k], w1[k * 64 + t], acc);
    a[t] = fmaxf(acc, 0.f);
    __syncthreads();
    if (t < 10) {
        float s = b2[t];
        for (int k = 0; k < 64; ++k) s = fmaf(a[k], w2[k * 10 + t], s);
        o[t] = s;
    }
    __syncthreads();
    if (t == 0) {
        float m = -INFINITY;
        for (int c = 0; c < 10; ++c) m = fmaxf(m, o[c]);
        float se = 0.f;
        for (int c = 0; c < 10; ++c) se += expf(o[c] - m);
        red[0] = m;
        red[1] = logf(se);
    }
    __syncthreads();
    if (t < 10) out[g * 10 + t] = o[t] - red[0] - red[1];
}

extern "C" void kernel_launch(void* const* d_in, const int* in_sizes, int n_in,
                              void* d_out, int out_size, void* d_ws, size_t ws_size,
                              hipStream_t stream) {
    const float* x    = (const float*)d_in[0];
    const int* ei     = (const int*)d_in[1];
    const int* batch  = (const int*)d_in[2];
    const float* g1w1 = (const float*)d_in[3];  const float* g1b1 = (const float*)d_in[4];
    const float* g1w2 = (const float*)d_in[5];  const float* g1b2 = (const float*)d_in[6];
    const float* g2w1 = (const float*)d_in[7];  const float* g2b1 = (const float*)d_in[8];
    const float* g2w2 = (const float*)d_in[9];  const float* g2b2 = (const float*)d_in[10];
    const float* g3w1 = (const float*)d_in[11]; const float* g3b1 = (const float*)d_in[12];
    const float* g3w2 = (const float*)d_in[13]; const float* g3b2 = (const float*)d_in[14];
    const float* f1w  = (const float*)d_in[15]; const float* f1b  = (const float*)d_in[16];
    const float* f2w  = (const float*)d_in[17]; const float* f2b  = (const float*)d_in[18];
    float* out = (float*)d_out;

    const int N = NNODES;
    const int E = in_sizes[1] / 2;

    char* base = (char*)d_ws;
    auto alloc = [&](size_t bytes) { char* p = base; base += (bytes + 255) & ~(size_t)255; return p; };

    unsigned short* B1 = (unsigned short*)alloc((size_t)N * 128 * 2);
    unsigned short* B2 = (unsigned short*)alloc((size_t)N * 128 * 2);
    unsigned short* B0 = (unsigned short*)alloc((size_t)N * 64 * 2);   // x bf16 sliced[4]
    // B3 (layer-1 gather out, 12.8MB) aliases binned (NB*CAP*4 = 9.63MB):
    // binned is dead before B3's first write.
    char* shared_region = alloc((size_t)N * 64 * 2);
    unsigned short* B3 = (unsigned short*)shared_region;
    unsigned int* binned = (unsigned int*)shared_region;
    int* csr      = (int*)alloc((size_t)E * 4);
    int* start    = (int*)alloc((size_t)(N + 1) * 4);
    int* gcur     = (int*)alloc((size_t)(NB + 4) * 4);
    int* bbase    = (int*)alloc((size_t)(NB + 4) * 4);
    float* pooled = (float*)alloc((size_t)NGRAPHS * 128 * 4);
    unsigned short* wp1 = (unsigned short*)alloc((size_t)64 * 128 * 2);
    unsigned short* wp2 = (unsigned short*)alloc((size_t)128 * 128 * 2);
    unsigned short* wp3 = (unsigned short*)alloc((size_t)128 * 128 * 2);
    unsigned short* wp4 = (unsigned short*)alloc((size_t)128 * 128 * 2);
    unsigned short* wp5 = (unsigned short*)alloc((size_t)128 * 128 * 2);
    unsigned short* wp6 = (unsigned short*)alloc((size_t)128 * 128 * 2);

    // ---- CSR build ----
    init_gcur<<<1, 128, 0, stream>>>(gcur);
    bin_kernel<<<(E + BIN_CHUNK - 1) / BIN_CHUNK, 256, 0, stream>>>(binned, gcur, ei, E);
    bucket_scan<<<1, 64, 0, stream>>>(bbase, gcur);
    fill2_kernel<<<NB, 256, 0, stream>>>(csr, start, binned, gcur, bbase, N);

    // ---- conversions / packs ----
    convert_kernel<<<(N * 8 + 255) / 256, 256, 0, stream>>>((u32x4*)B0, x, N);
    pack_w_kernel<<<4, 256, 0, stream>>>(wp1, g1w1, 64);
    pack_w_kernel<<<8, 256, 0, stream>>>(wp2, g1w2, 128);
    pack_w_kernel<<<8, 256, 0, stream>>>(wp3, g2w1, 128);
    pack_w_kernel<<<8, 256, 0, stream>>>(wp4, g2w2, 128);
    pack_w_kernel<<<8, 256, 0, stream>>>(wp5, g3w1, 128);
    pack_w_kernel<<<8, 256, 0, stream>>>(wp6, g3w2, 128);
    init_pool_kernel<<<(NGRAPHS * 128 + 255) / 256, 256, 0, stream>>>(pooled);

    const int pgrid = (N + 63) / 64;
    const int gblk = (N + 127) / 128;

    // ---- layer 1 (K=64, NSL=4) ----
    gather_sliced<4><<<4 * gblk, 256, 0, stream>>>((u32x4*)B3, (const u32x4*)B0, start, csr, N);
    mfma_gemm_pair<64><<<pgrid, 256, 0, stream>>>(B3, wp1, g1b1, wp2, g1b2, B1, N);

    // ---- layer 2 (NSL=8) ----
    gather_sliced<8><<<8 * gblk, 256, 0, stream>>>((u32x4*)B2, (const u32x4*)B1, start, csr, N);
    mfma_gemm_pair<128><<<pgrid, 256, 0, stream>>>(B2, wp3, g2b1, wp4, g2b2, B1, N);

    // ---- layer 3 (NSL=8) ----
    gather_sliced<8><<<8 * gblk, 256, 0, stream>>>((u32x4*)B2, (const u32x4*)B1, start, csr, N);
    mfma_gemm_pair<128><<<pgrid, 256, 0, stream>>>(B2, wp5, g3b1, wp6, g3b2, B1, N);

    // ---- pool + head ----
    pool_kernel<<<(N + 127) / 128, 128, 0, stream>>>(pooled, B1, batch, N);
    head_kernel<<<NGRAPHS, 64, 0, stream>>>(out, pooled, f1w, f1b, f2w, f2b);
}

// Round 8
// 375.960 us; speedup vs baseline: 1.8786x; 1.8786x over previous
//
#include <hip/hip_runtime.h>
#include <hip/hip_bf16.h>
#include <cmath>

#define NNODES 100000
#define NGRAPHS 64
#define SHIFT 10
#define NPB 1024                 // nodes per bucket
#define NB 98                    // ceil(NNODES / NPB)
#define CAP 24576                // max edges per bucket region (exp 16384 +- 128)
#define BIN_CHUNK 4096
#define HSTRIDE 136              // LDS row stride in shorts (272B, 16B-aligned rows)

typedef __attribute__((ext_vector_type(8))) short bf16x8;
typedef __attribute__((ext_vector_type(4))) float f32x4;
typedef __attribute__((ext_vector_type(4))) unsigned int u32x4;

__device__ __forceinline__ float bf2f(unsigned short u) {
    unsigned int v = ((unsigned int)u) << 16;
    return __uint_as_float(v);
}
__device__ __forceinline__ unsigned short f2bf(float f) {
    unsigned int v = __float_as_uint(f);
    unsigned int r = (v + 0x7fffu + ((v >> 16) & 1u)) >> 16;
    return (unsigned short)r;
}

__device__ __forceinline__ void atomicMaxF(float* addr, float v) {
    if (v >= 0.f) atomicMax((int*)addr, __float_as_int(v));
    else          atomicMin((unsigned int*)addr, __float_as_uint(v));
}

// ---------------- x (f32) -> bf16 ----------------
__global__ void convert_kernel(unsigned short* __restrict__ dst, const float* __restrict__ src, int n4) {
    int i = blockIdx.x * blockDim.x + threadIdx.x;
    if (i >= n4) return;
    float4 v = ((const float4*)src)[i];
    unsigned short o[4] = { f2bf(v.x), f2bf(v.y), f2bf(v.z), f2bf(v.w) };
    ((uint2*)dst)[i] = *(uint2*)o;
}

// ---------------- CSR build (binned, no global histogram) ----------------
__global__ void init_gcur(int* __restrict__ gcur) {
    int b = threadIdx.x;
    if (b < NB) gcur[b] = b * CAP;
}

__global__ __launch_bounds__(256) void bin_kernel(unsigned int* __restrict__ binned,
                                                  int* __restrict__ gcur,
                                                  const int* __restrict__ ei, int E) {
    __shared__ int cnt[NB];
    __shared__ int gbase[NB];
    __shared__ int loff[NB];
    int t = threadIdx.x;
    int base = blockIdx.x * BIN_CHUNK;
    for (int i = t; i < NB; i += 256) { cnt[i] = 0; loff[i] = 0; }
    __syncthreads();
    unsigned int pk[16]; short bk[16]; int ne = 0;
#pragma unroll
    for (int i = 0; i < 16; ++i) {
        int e = base + t + i * 256;
        if (e < E) {
            int s = ei[e], d = ei[E + e];
            int b = d >> SHIFT;
            pk[ne] = ((unsigned int)s << SHIFT) | (unsigned int)(d & (NPB - 1));
            bk[ne] = (short)b;
            ne++;
            atomicAdd(&cnt[b], 1);
        }
    }
    __syncthreads();
    for (int i = t; i < NB; i += 256)
        gbase[i] = cnt[i] ? atomicAdd(&gcur[i], cnt[i]) : 0;
    __syncthreads();
    for (int i = 0; i < ne; ++i) {
        int b = bk[i];
        int pos = atomicAdd(&loff[b], 1);
        binned[gbase[b] + pos] = pk[i];
    }
}

__global__ void bucket_scan(int* __restrict__ bbase, const int* __restrict__ gcur) {
    if (threadIdx.x == 0 && blockIdx.x == 0) {
        int acc = 0;
        for (int b = 0; b < NB; ++b) { bbase[b] = acc; acc += gcur[b] - b * CAP; }
        bbase[NB] = acc;
    }
}

__global__ __launch_bounds__(256) void fill2_kernel(int* __restrict__ csr,
                                                    int* __restrict__ start,
                                                    const unsigned int* __restrict__ binned,
                                                    const int* __restrict__ gcur,
                                                    const int* __restrict__ bbase, int N) {
    __shared__ int cur[NPB];
    __shared__ int tsum[256];
    int b = blockIdx.x, t = threadIdx.x;
    int n0 = b << SHIFT;
    int nn = N - n0; if (nn > NPB) nn = NPB;
    int c = gcur[b] - b * CAP;
    int gb = bbase[b];
    const unsigned int* eb = binned + (size_t)b * CAP;
    for (int i = t; i < NPB; i += 256) cur[i] = 0;
    __syncthreads();
    for (int p = t; p < c; p += 256) atomicAdd(&cur[eb[p] & (NPB - 1)], 1);
    __syncthreads();
    int v[4]; int s = 0;
#pragma unroll
    for (int i = 0; i < 4; ++i) { v[i] = cur[t * 4 + i]; s += v[i]; }
    int x = s;
    tsum[t] = x;
    __syncthreads();
    for (int off = 1; off < 256; off <<= 1) {
        int y = (t >= off) ? tsum[t - off] : 0;
        __syncthreads();
        x += y;
        tsum[t] = x;
        __syncthreads();
    }
    int run = x - s + gb;
#pragma unroll
    for (int i = 0; i < 4; ++i) {
        int idx = t * 4 + i;
        cur[idx] = run;
        if (idx < nn) start[n0 + idx] = run;
        run += v[i];
    }
    __syncthreads();
    for (int p = t; p < c; p += 256) {
        unsigned int e = eb[p];
        int slot = atomicAdd(&cur[e & (NPB - 1)], 1);
        csr[slot] = (int)(e >> SHIFT);
    }
    if (t == 0 && b == 0) start[N] = bbase[NB];
}

// ---------------- aggregation (bf16): out[i] = h[i] + sum_j h[j] ----------------
// LANES lanes per node, each lane owns 8 bf16 (16B); D = LANES*8.
// csr loads are cooperative: each lane loads a different entry, broadcast by shfl.
template<int LANES>
__global__ __launch_bounds__(256) void gather_kernel(unsigned short* __restrict__ outb,
                                                     const unsigned short* __restrict__ h,
                                                     const int* __restrict__ start,
                                                     const int* __restrict__ csr, int N) {
    const int D = LANES * 8;
    int t = threadIdx.x;
    int node = blockIdx.x * (256 / LANES) + t / LANES;
    if (node >= N) return;
    int lane = t % LANES;
    float acc[8];
    {
        u32x4 v = *(const u32x4*)(h + (size_t)node * D + lane * 8);
        const unsigned short* q = (const unsigned short*)&v;
#pragma unroll
        for (int i = 0; i < 8; ++i) acc[i] = bf2f(q[i]);
    }
    int p0 = start[node], p1 = start[node + 1];
    for (int pb = p0; pb < p1; pb += LANES) {
        int cnt = p1 - pb;
        int myj = (pb + lane < p1) ? csr[pb + lane] : 0;
        if (cnt >= LANES) {
#pragma unroll
            for (int i = 0; i < LANES; ++i) {
                int j = __shfl(myj, i, LANES);
                u32x4 v = *(const u32x4*)(h + (size_t)j * D + lane * 8);
                const unsigned short* q = (const unsigned short*)&v;
#pragma unroll
                for (int k = 0; k < 8; ++k) acc[k] += bf2f(q[k]);
            }
        } else {
            for (int i = 0; i < cnt; ++i) {
                int j = __shfl(myj, i, LANES);
                u32x4 v = *(const u32x4*)(h + (size_t)j * D + lane * 8);
                const unsigned short* q = (const unsigned short*)&v;
#pragma unroll
                for (int k = 0; k < 8; ++k) acc[k] += bf2f(q[k]);
            }
        }
    }
    unsigned short o[8];
#pragma unroll
    for (int i = 0; i < 8; ++i) o[i] = f2bf(acc[i]);
    *(u32x4*)(outb + (size_t)node * D + lane * 8) = *(u32x4*)o;
}

// ---------------- W (K x 128 f32) -> MFMA B-fragment pack (bf16) ----------------
__global__ void pack_w_kernel(unsigned short* __restrict__ wp, const float* __restrict__ W, int K) {
    int t = blockIdx.x * blockDim.x + threadIdx.x;
    int total = (K / 32) * 8 * 64;
    if (t >= total) return;
    int l = t & 63;
    int n0 = (t >> 6) & 7;
    int kp = t >> 9;
    unsigned short o[8];
#pragma unroll
    for (int j = 0; j < 8; ++j)
        o[j] = f2bf(W[(size_t)(kp * 32 + (l >> 4) * 8 + j) * 128 + n0 * 16 + (l & 15)]);
    *(u32x4*)(wp + (size_t)t * 8) = *(u32x4*)o;
}

// ---------------- fused MLP: out = (relu(A@W1+b1))@W2 + b2, all M x 128 ----------------
template<int K1>
__global__ __launch_bounds__(256) void mfma_gemm_pair(const unsigned short* __restrict__ A,
                                                      const unsigned short* __restrict__ Wp1,
                                                      const float* __restrict__ bias1,
                                                      const unsigned short* __restrict__ Wp2,
                                                      const float* __restrict__ bias2,
                                                      unsigned short* __restrict__ out, int M) {
    __shared__ unsigned short hl[4][16 * HSTRIDE];
    const int l = threadIdx.x & 63;
    const int w = threadIdx.x >> 6;
    const int mbase = (blockIdx.x * 4 + w) * 16;
    const int kgrp = l >> 4;
    const int col = l & 15;
    int row_a = mbase + col;
    if (row_a >= M) row_a = M - 1;

    f32x4 acc[8];
#pragma unroll
    for (int i = 0; i < 8; ++i) acc[i] = (f32x4){0.f, 0.f, 0.f, 0.f};
#pragma unroll
    for (int kp = 0; kp < K1 / 32; ++kp) {
        bf16x8 a = *(const bf16x8*)(A + (size_t)row_a * K1 + kp * 32 + kgrp * 8);
#pragma unroll
        for (int n0 = 0; n0 < 8; ++n0) {
            bf16x8 bfr = *(const bf16x8*)(Wp1 + ((size_t)(kp * 8 + n0) * 64 + l) * 8);
            acc[n0] = __builtin_amdgcn_mfma_f32_16x16x32_bf16(a, bfr, acc[n0], 0, 0, 0);
        }
    }

    unsigned short* hb = hl[w];
#pragma unroll
    for (int n0 = 0; n0 < 8; ++n0) {
        float bv = bias1[n0 * 16 + col];
#pragma unroll
        for (int r = 0; r < 4; ++r) {
            float v = acc[n0][r] + bv;
            v = fmaxf(v, 0.f);
            hb[(kgrp * 4 + r) * HSTRIDE + n0 * 16 + col] = f2bf(v);
        }
    }
    __syncthreads();

    f32x4 acc2[8];
#pragma unroll
    for (int i = 0; i < 8; ++i) acc2[i] = (f32x4){0.f, 0.f, 0.f, 0.f};
#pragma unroll
    for (int kp = 0; kp < 4; ++kp) {
        bf16x8 a2 = *(const bf16x8*)(hb + col * HSTRIDE + kp * 32 + kgrp * 8);
#pragma unroll
        for (int n0 = 0; n0 < 8; ++n0) {
            bf16x8 bfr = *(const bf16x8*)(Wp2 + ((size_t)(kp * 8 + n0) * 64 + l) * 8);
            acc2[n0] = __builtin_amdgcn_mfma_f32_16x16x32_bf16(a2, bfr, acc2[n0], 0, 0, 0);
        }
    }

#pragma unroll
    for (int n0 = 0; n0 < 8; ++n0) {
        float bv = bias2[n0 * 16 + col];
#pragma unroll
        for (int r = 0; r < 4; ++r) {
            int row = mbase + kgrp * 4 + r;
            if (row < M)
                out[(size_t)row * 128 + n0 * 16 + col] = f2bf(acc2[n0][r] + bv);
        }
    }
}

// ---------------- pool + head ----------------
__global__ void init_pool_kernel(float* p) {
    int i = blockIdx.x * blockDim.x + threadIdx.x;
    if (i < NGRAPHS * 128) p[i] = -INFINITY;
}

__global__ __launch_bounds__(128) void pool_kernel(float* __restrict__ pooled,
                                                   const unsigned short* __restrict__ h,
                                                   const int* __restrict__ batch, int N) {
    const int f = threadIdx.x;
    int n0 = blockIdx.x * 128;
    int n1 = n0 + 128;
    if (n1 > N) n1 = N;
    int cur = -1;
    float run = -INFINITY;
    for (int n = n0; n < n1; ++n) {
        int g = batch[n];
        if (g != cur) {
            if (cur >= 0) atomicMaxF(&pooled[cur * 128 + f], run);
            cur = g;
            run = -INFINITY;
        }
        run = fmaxf(run, bf2f(h[(size_t)n * 128 + f]));
    }
    if (cur >= 0) atomicMaxF(&pooled[cur * 128 + f], run);
}

__global__ __launch_bounds__(64) void head_kernel(float* __restrict__ out,
                                                  const float* __restrict__ pooled,
                                                  const float* __restrict__ w1,
                                                  const float* __restrict__ b1,
                                                  const float* __restrict__ w2,
                                                  const float* __restrict__ b2) {
    int g = blockIdx.x, t = threadIdx.x;
    __shared__ float a[64];
    __shared__ float o[10];
    __shared__ float red[2];
    const float* pg = pooled + g * 128;
    float acc = b1[t];
    for (int k = 0; k < 128; ++k) acc = fmaf(pg[k], w1[k * 64 + t], acc);
    a[t] = fmaxf(acc, 0.f);
    __syncthreads();
    if (t < 10) {
        float s = b2[t];
        for (int k = 0; k < 64; ++k) s = fmaf(a[k], w2[k * 10 + t], s);
        o[t] = s;
    }
    __syncthreads();
    if (t == 0) {
        float m = -INFINITY;
        for (int c = 0; c < 10; ++c) m = fmaxf(m, o[c]);
        float se = 0.f;
        for (int c = 0; c < 10; ++c) se += expf(o[c] - m);
        red[0] = m;
        red[1] = logf(se);
    }
    __syncthreads();
    if (t < 10) out[g * 10 + t] = o[t] - red[0] - red[1];
}

extern "C" void kernel_launch(void* const* d_in, const int* in_sizes, int n_in,
                              void* d_out, int out_size, void* d_ws, size_t ws_size,
                              hipStream_t stream) {
    const float* x    = (const float*)d_in[0];
    const int* ei     = (const int*)d_in[1];
    const int* batch  = (const int*)d_in[2];
    const float* g1w1 = (const float*)d_in[3];  const float* g1b1 = (const float*)d_in[4];
    const float* g1w2 = (const float*)d_in[5];  const float* g1b2 = (const float*)d_in[6];
    const float* g2w1 = (const float*)d_in[7];  const float* g2b1 = (const float*)d_in[8];
    const float* g2w2 = (const float*)d_in[9];  const float* g2b2 = (const float*)d_in[10];
    const float* g3w1 = (const float*)d_in[11]; const float* g3b1 = (const float*)d_in[12];
    const float* g3w2 = (const float*)d_in[13]; const float* g3b2 = (const float*)d_in[14];
    const float* f1w  = (const float*)d_in[15]; const float* f1b  = (const float*)d_in[16];
    const float* f2w  = (const float*)d_in[17]; const float* f2b  = (const float*)d_in[18];
    float* out = (float*)d_out;

    const int N = NNODES;
    const int E = in_sizes[1] / 2;

    char* base = (char*)d_ws;
    auto alloc = [&](size_t bytes) { char* p = base; base += (bytes + 255) & ~(size_t)255; return p; };

    unsigned short* B1 = (unsigned short*)alloc((size_t)N * 128 * 2);
    unsigned short* B2 = (unsigned short*)alloc((size_t)N * 128 * 2);
    unsigned short* B0 = (unsigned short*)alloc((size_t)N * 64 * 2);   // x bf16
    // B3 (layer-1 gather out, 12.8MB) aliases binned (NB*CAP*4 = 9.63MB):
    // binned is dead before B3's first write.
    char* shared_region = alloc((size_t)N * 64 * 2);
    unsigned short* B3 = (unsigned short*)shared_region;
    unsigned int* binned = (unsigned int*)shared_region;
    int* csr      = (int*)alloc((size_t)E * 4);
    int* start    = (int*)alloc((size_t)(N + 1) * 4);
    int* gcur     = (int*)alloc((size_t)(NB + 4) * 4);
    int* bbase    = (int*)alloc((size_t)(NB + 4) * 4);
    float* pooled = (float*)alloc((size_t)NGRAPHS * 128 * 4);
    unsigned short* wp1 = (unsigned short*)alloc((size_t)64 * 128 * 2);
    unsigned short* wp2 = (unsigned short*)alloc((size_t)128 * 128 * 2);
    unsigned short* wp3 = (unsigned short*)alloc((size_t)128 * 128 * 2);
    unsigned short* wp4 = (unsigned short*)alloc((size_t)128 * 128 * 2);
    unsigned short* wp5 = (unsigned short*)alloc((size_t)128 * 128 * 2);
    unsigned short* wp6 = (unsigned short*)alloc((size_t)128 * 128 * 2);

    // ---- CSR build ----
    init_gcur<<<1, 128, 0, stream>>>(gcur);
    bin_kernel<<<(E + BIN_CHUNK - 1) / BIN_CHUNK, 256, 0, stream>>>(binned, gcur, ei, E);
    bucket_scan<<<1, 64, 0, stream>>>(bbase, gcur);
    fill2_kernel<<<NB, 256, 0, stream>>>(csr, start, binned, gcur, bbase, N);

    // ---- conversions / packs ----
    convert_kernel<<<(N * 64 / 4 + 255) / 256, 256, 0, stream>>>(B0, x, N * 64 / 4);
    pack_w_kernel<<<4, 256, 0, stream>>>(wp1, g1w1, 64);
    pack_w_kernel<<<8, 256, 0, stream>>>(wp2, g1w2, 128);
    pack_w_kernel<<<8, 256, 0, stream>>>(wp3, g2w1, 128);
    pack_w_kernel<<<8, 256, 0, stream>>>(wp4, g2w2, 128);
    pack_w_kernel<<<8, 256, 0, stream>>>(wp5, g3w1, 128);
    pack_w_kernel<<<8, 256, 0, stream>>>(wp6, g3w2, 128);
    init_pool_kernel<<<(NGRAPHS * 128 + 255) / 256, 256, 0, stream>>>(pooled);

    const int pgrid = (N + 63) / 64;

    // ---- layer 1 (K=64) ----
    gather_kernel<8><<<(N + 31) / 32, 256, 0, stream>>>(B3, B0, start, csr, N);
    mfma_gemm_pair<64><<<pgrid, 256, 0, stream>>>(B3, wp1, g1b1, wp2, g1b2, B1, N);

    // ---- layer 2 ----
    gather_kernel<16><<<(N + 15) / 16, 256, 0, stream>>>(B2, B1, start, csr, N);
    mfma_gemm_pair<128><<<pgrid, 256, 0, stream>>>(B2, wp3, g2b1, wp4, g2b2, B1, N);

    // ---- layer 3 ----
    gather_kernel<16><<<(N + 15) / 16, 256, 0, stream>>>(B2, B1, start, csr, N);
    mfma_gemm_pair<128><<<pgrid, 256, 0, stream>>>(B2, wp5, g3b1, wp6, g3b2, B1, N);

    // ---- pool + head ----
    pool_kernel<<<(N + 127) / 128, 128, 0, stream>>>(pooled, B1, batch, N);
    head_kernel<<<NGRAPHS, 64, 0, stream>>>(out, pooled, f1w, f1b, f2w, f2b);
}